// Round 1
// baseline (7016.058 us; speedup 1.0000x reference)
//
#include <hip/hip_runtime.h>
#include <math.h>

#define B_TOT 4096
#define CHUNK 1024

// ---------------------------------------------------------------------------
// Fused: patch conv (1->32, k4 s4) + 2 transformer blocks. One block / sample.
// ---------------------------------------------------------------------------
__global__ __launch_bounds__(256) void k_tokens(
    const float* __restrict__ x, const float* __restrict__ pw, const float* __restrict__ pb,
    const float* __restrict__ ln1g, const float* __restrict__ ln1b,
    const float* __restrict__ wi, const float* __restrict__ bi,
    const float* __restrict__ wo, const float* __restrict__ bo,
    const float* __restrict__ ln2g, const float* __restrict__ ln2b,
    const float* __restrict__ w1, const float* __restrict__ b1,
    const float* __restrict__ w2, const float* __restrict__ b2,
    float* __restrict__ tokens)
{
    __shared__ float t_s[1568];    // tokens [49][32]
    __shared__ float xn_s[1568];   // LN out / attn out
    __shared__ float w_s[4224];    // staged weights (padded layouts)
    __shared__ float u_s[7200];    // x patch | qkv[49][97] + scores | ff hidden [49][128]
    const int b = blockIdx.x, tid = threadIdx.x;

    // ---- patch embed: t[s][c] = sum_{ky,kx} x[py*4+ky][px*4+kx] * pw[c][ky][kx] + pb[c]
    for (int e = tid; e < 784; e += 256) u_s[e] = x[(size_t)b * 784 + e];
    for (int e = tid; e < 512; e += 256) { int c = e >> 4, t = e & 15; w_s[c * 17 + t] = pw[e]; }
    __syncthreads();
    for (int e = tid; e < 1568; e += 256) {
        int s = e >> 5, c = e & 31;
        int py = s / 7, px = s % 7;
        float acc = pb[c];
        for (int ky = 0; ky < 4; ++ky)
            for (int kx = 0; kx < 4; ++kx)
                acc += u_s[(py * 4 + ky) * 28 + px * 4 + kx] * w_s[c * 17 + ky * 4 + kx];
        t_s[e] = acc;
    }
    __syncthreads();

    for (int blk = 0; blk < 2; ++blk) {
        // ---- LN1 (49 tokens, lanes 0..48)
        if (tid < 49) {
            const float* g = ln1g + blk * 32; const float* bb = ln1b + blk * 32;
            float m = 0.f;
            for (int c = 0; c < 32; ++c) m += t_s[tid * 32 + c];
            m *= (1.f / 32.f);
            float v = 0.f;
            for (int c = 0; c < 32; ++c) { float d = t_s[tid * 32 + c] - m; v += d * d; }
            v *= (1.f / 32.f);
            float rstd = rsqrtf(v + 1e-5f);
            for (int c = 0; c < 32; ++c)
                xn_s[tid * 32 + c] = (t_s[tid * 32 + c] - m) * rstd * g[c] + bb[c];
        }
        __syncthreads();
        // ---- stage wi transposed+padded: w_s[k*97+j] = wi[j][k]
        for (int e = tid; e < 3072; e += 256) { int j = e >> 5, k = e & 31; w_s[k * 97 + j] = wi[blk * 3072 + e]; }
        __syncthreads();
        // ---- qkv[s][j] at u_s[s*97+j]
        for (int e = tid; e < 4704; e += 256) {
            int s = e / 96, j = e % 96;
            float acc = bi[blk * 96 + j];
            for (int k = 0; k < 32; ++k) acc += xn_s[s * 32 + k] * w_s[k * 97 + j];
            u_s[s * 97 + j] = acc;
        }
        __syncthreads();
        // ---- attention, per head
        float* sc = u_s + 4768;
        for (int h = 0; h < 2; ++h) {
            int qo = h * 16, ko = 32 + h * 16, vo = 64 + h * 16;
            for (int e = tid; e < 2401; e += 256) {
                int i = e / 49, jq = e % 49;
                float acc = 0.f;
                for (int d = 0; d < 16; ++d) acc += u_s[i * 97 + qo + d] * u_s[jq * 97 + ko + d];
                sc[e] = acc * 0.25f;   // 1/sqrt(16)
            }
            __syncthreads();
            if (tid < 49) {  // softmax row
                float mx = -1e30f;
                for (int j = 0; j < 49; ++j) mx = fmaxf(mx, sc[tid * 49 + j]);
                float sum = 0.f;
                for (int j = 0; j < 49; ++j) { float ev = expf(sc[tid * 49 + j] - mx); sc[tid * 49 + j] = ev; sum += ev; }
                float inv = 1.f / sum;
                for (int j = 0; j < 49; ++j) sc[tid * 49 + j] *= inv;
            }
            __syncthreads();
            for (int e = tid; e < 784; e += 256) {
                int i = e >> 4, d = e & 15;
                float acc = 0.f;
                for (int jq = 0; jq < 49; ++jq) acc += sc[i * 49 + jq] * u_s[jq * 97 + vo + d];
                xn_s[i * 32 + qo + d] = acc;
            }
            __syncthreads();
        }
        // ---- out proj + residual: w_s[e*33+c] = wo[c][e]
        for (int e = tid; e < 1024; e += 256) { int c = e >> 5, ei = e & 31; w_s[ei * 33 + c] = wo[blk * 1024 + e]; }
        __syncthreads();
        for (int e = tid; e < 1568; e += 256) {
            int s = e >> 5, c = e & 31;
            float acc = bo[blk * 32 + c];
            for (int k = 0; k < 32; ++k) acc += xn_s[s * 32 + k] * w_s[k * 33 + c];
            t_s[e] += acc;
        }
        __syncthreads();
        // ---- LN2
        if (tid < 49) {
            const float* g = ln2g + blk * 32; const float* bb = ln2b + blk * 32;
            float m = 0.f;
            for (int c = 0; c < 32; ++c) m += t_s[tid * 32 + c];
            m *= (1.f / 32.f);
            float v = 0.f;
            for (int c = 0; c < 32; ++c) { float d = t_s[tid * 32 + c] - m; v += d * d; }
            v *= (1.f / 32.f);
            float rstd = rsqrtf(v + 1e-5f);
            for (int c = 0; c < 32; ++c)
                xn_s[tid * 32 + c] = (t_s[tid * 32 + c] - m) * rstd * g[c] + bb[c];
        }
        __syncthreads();
        // ---- FF1 + exact GELU: w_s[k*129+j] = w1[j][k]
        for (int e = tid; e < 4096; e += 256) { int j = e >> 5, k = e & 31; w_s[k * 129 + j] = w1[blk * 4096 + e]; }
        __syncthreads();
        for (int e = tid; e < 6272; e += 256) {
            int s = e >> 7, j = e & 127;
            float acc = b1[blk * 128 + j];
            for (int k = 0; k < 32; ++k) acc += xn_s[s * 32 + k] * w_s[k * 129 + j];
            acc = 0.5f * acc * (1.f + erff(acc * 0.7071067811865476f));
            u_s[e] = acc;   // h[s][j] at s*128+j
        }
        __syncthreads();
        // ---- FF2 + residual: w_s[k*33+c] = w2[c][k]
        for (int e = tid; e < 4096; e += 256) { int c = e >> 7, k = e & 127; w_s[k * 33 + c] = w2[blk * 4096 + e]; }
        __syncthreads();
        for (int e = tid; e < 1568; e += 256) {
            int s = e >> 5, c = e & 31;
            float acc = b2[blk * 32 + c];
            for (int k = 0; k < 128; ++k) acc += u_s[s * 128 + k] * w_s[k * 33 + c];
            t_s[e] += acc;
        }
        __syncthreads();
    }
    for (int e = tid; e < 1568; e += 256) tokens[(size_t)b * 1568 + e] = t_s[e];
}

// ---------------------------------------------------------------------------
// C[M,N] = A[M,K] @ B[N,K]^T (+bias). 64x64 tile, BK=16, 4x4 microtile.
// ---------------------------------------------------------------------------
__global__ __launch_bounds__(256) void k_gemm(
    const float* __restrict__ A, const float* __restrict__ Bm,
    const float* __restrict__ bias, float* __restrict__ C,
    int M, int N, int K)
{
    __shared__ float As[16 * 68];  // [k][m], stride 68 (16B-aligned rows, conflict-free)
    __shared__ float Bs[16 * 68];  // [k][n]
    const int n0 = blockIdx.x * 64, m0 = blockIdx.y * 64;
    const int tid = threadIdx.x;
    const int tx = tid & 15, ty = tid >> 4;
    float acc[4][4] = {{0.f}};
    for (int k0 = 0; k0 < K; k0 += 16) {
        for (int l = 0; l < 4; ++l) {
            int idx = tid + l * 256;
            int m = idx >> 4, k = idx & 15;
            As[k * 68 + m] = A[(size_t)(m0 + m) * K + k0 + k];
            Bs[k * 68 + m] = Bm[(size_t)(n0 + m) * K + k0 + k];
        }
        __syncthreads();
        for (int k = 0; k < 16; ++k) {
            float4 av = *(const float4*)&As[k * 68 + ty * 4];
            float4 bv = *(const float4*)&Bs[k * 68 + tx * 4];
            float a4[4] = {av.x, av.y, av.z, av.w};
            float b4[4] = {bv.x, bv.y, bv.z, bv.w};
            for (int i = 0; i < 4; ++i)
                for (int j = 0; j < 4; ++j)
                    acc[i][j] += a4[i] * b4[j];
        }
        __syncthreads();
    }
    for (int i = 0; i < 4; ++i) {
        int m = m0 + ty * 4 + i;
        for (int j = 0; j < 4; ++j) {
            int n = n0 + tx * 4 + j;
            float v = acc[i][j] + (bias ? bias[n] : 0.f);
            C[(size_t)m * N + n] = v;
        }
    }
}

// ---------------------------------------------------------------------------
// inverse (clipped) L2 norm of each memory row [4096,256]
// ---------------------------------------------------------------------------
__global__ __launch_bounds__(256) void k_mnorm(const float* __restrict__ mem, float* __restrict__ inv_norm)
{
    __shared__ float red[256];
    const int row = blockIdx.x, tid = threadIdx.x;
    float v = mem[(size_t)row * 256 + tid];
    red[tid] = v * v;
    __syncthreads();
    for (int s = 128; s > 0; s >>= 1) {
        if (tid < s) red[tid] += red[tid + s];
        __syncthreads();
    }
    if (tid == 0) inv_norm[row] = 1.f / fmaxf(sqrtf(red[0]), 1e-12f);
}

// ---------------------------------------------------------------------------
// top-10 over normalized sims + softmax-weighted gather of memory rows
// ---------------------------------------------------------------------------
__global__ __launch_bounds__(256) void k_memread(
    const float* __restrict__ latent, const float* __restrict__ dots,
    const float* __restrict__ inv_mn, const float* __restrict__ mem,
    float* __restrict__ out)
{
    __shared__ float red[256];
    __shared__ int   redi[256];
    __shared__ float inv_x_s;
    const int b = blockIdx.x, tid = threadIdx.x;
    float lx = latent[(size_t)b * 256 + tid];
    red[tid] = lx * lx;
    __syncthreads();
    for (int s = 128; s > 0; s >>= 1) {
        if (tid < s) red[tid] += red[tid + s];
        __syncthreads();
    }
    if (tid == 0) inv_x_s = 1.f / fmaxf(sqrtf(red[0]), 1e-12f);
    __syncthreads();
    const float inv_x = inv_x_s;

    float vals[16];
    for (int j = 0; j < 16; ++j) {
        int m = tid + j * 256;
        vals[j] = dots[(size_t)b * 4096 + m] * inv_mn[m] * inv_x;
    }
    float tv[10]; int ti[10];
    for (int t = 0; t < 10; ++t) {
        float bv = -1e30f; int bidx = 0x7fffffff;
        for (int j = 0; j < 16; ++j) {
            int m = tid + j * 256;
            float v = vals[j];
            if (v > bv || (v == bv && m < bidx)) { bv = v; bidx = m; }
        }
        red[tid] = bv; redi[tid] = bidx;
        __syncthreads();
        for (int s = 128; s > 0; s >>= 1) {
            if (tid < s) {
                float v2 = red[tid + s]; int i2 = redi[tid + s];
                if (v2 > red[tid] || (v2 == red[tid] && i2 < redi[tid])) { red[tid] = v2; redi[tid] = i2; }
            }
            __syncthreads();
        }
        int sel = redi[0];
        tv[t] = red[0]; ti[t] = sel;
        if ((sel & 255) == tid) vals[sel >> 8] = -1e30f;
        __syncthreads();
    }
    // softmax over the 10 (tv[0] is the max)
    float w[10], wsum = 0.f;
    for (int t = 0; t < 10; ++t) { w[t] = expf(tv[t] - tv[0]); wsum += w[t]; }
    float inv_ws = 1.f / wsum;
    float acc = 0.f;
    for (int t = 0; t < 10; ++t) acc += (w[t] * inv_ws) * mem[(size_t)ti[t] * 256 + tid];
    out[(size_t)b * 256 + tid] = acc;
}

// ---------------------------------------------------------------------------
// ConvTranspose2d 64->32, k4 s2 p1, 7x7 -> 14x14, ReLU. One block / sample.
// ---------------------------------------------------------------------------
__global__ __launch_bounds__(256) void k_convt1(
    const float* __restrict__ in, const float* __restrict__ w,
    const float* __restrict__ bias, float* __restrict__ out)
{
    __shared__ float in_s[64 * 49];
    __shared__ float w_s[8 * 32 * 16];
    __shared__ float out_s[32 * 196];
    const int b = blockIdx.x, tid = threadIdx.x;
    for (int e = tid; e < 3136; e += 256) in_s[e] = in[(size_t)b * 3136 + e];
    for (int e = tid; e < 6272; e += 256) out_s[e] = 0.f;
    __syncthreads();
    for (int cc = 0; cc < 64; cc += 8) {
        for (int e = tid; e < 4096; e += 256) w_s[e] = w[cc * 512 + e]; // [cl][o][ky][kx]
        __syncthreads();
        for (int e = tid; e < 6272; e += 256) {
            int o = e / 196, p = e % 196, y = p / 14, xx0 = p % 14;
            float acc = 0.f;
            int ky0 = (y + 1) & 1, kx0 = (xx0 + 1) & 1;
            for (int ky = ky0; ky < 4; ky += 2) {
                int iyn = y + 1 - ky;
                if (iyn < 0) break;
                int iy = iyn >> 1;
                if (iy > 6) continue;
                for (int kx = kx0; kx < 4; kx += 2) {
                    int ixn = xx0 + 1 - kx;
                    if (ixn < 0) break;
                    int ix = ixn >> 1;
                    if (ix > 6) continue;
                    const float* ip = &in_s[cc * 49 + iy * 7 + ix];
                    const float* wp = &w_s[o * 16 + ky * 4 + kx];
                    float a = 0.f;
                    for (int cl = 0; cl < 8; ++cl) a += ip[cl * 49] * wp[cl * 512];
                    acc += a;
                }
            }
            out_s[e] += acc;
        }
        __syncthreads();
    }
    for (int e = tid; e < 6272; e += 256) {
        int o = e / 196;
        out[(size_t)b * 6272 + e] = fmaxf(out_s[e] + bias[o], 0.f);
    }
}

// ---------------------------------------------------------------------------
// Conv2d 32->32, k3 p1, 14x14, ReLU. One block / sample.
// ---------------------------------------------------------------------------
__global__ __launch_bounds__(256) void k_conv1(
    const float* __restrict__ in, const float* __restrict__ w,
    const float* __restrict__ bias, float* __restrict__ out)
{
    __shared__ float in_s[32 * 196];
    __shared__ float w_s[32 * 32 * 9];
    const int b = blockIdx.x, tid = threadIdx.x;
    for (int e = tid; e < 6272; e += 256) in_s[e] = in[(size_t)b * 6272 + e];
    for (int e = tid; e < 9216; e += 256) w_s[e] = w[e];
    __syncthreads();
    for (int e = tid; e < 6272; e += 256) {
        int o = e / 196, p = e % 196, y = p / 14, xx = p % 14;
        float acc = bias[o];
        const float* wob = &w_s[o * 288];
        for (int c = 0; c < 32; ++c) {
            const float* ip = &in_s[c * 196];
            const float* wp = &wob[c * 9];
            for (int ky = 0; ky < 3; ++ky) {
                int yy = y + ky - 1;
                if (yy < 0 || yy > 13) continue;
                for (int kx = 0; kx < 3; ++kx) {
                    int x2 = xx + kx - 1;
                    if (x2 < 0 || x2 > 13) continue;
                    acc += ip[yy * 14 + x2] * wp[ky * 3 + kx];
                }
            }
        }
        out[(size_t)b * 6272 + e] = fmaxf(acc, 0.f);
    }
}

// ---------------------------------------------------------------------------
// ConvTranspose2d 32->16, k4 s2 p1, 14x14 -> 28x28, ReLU. One block / sample.
// ---------------------------------------------------------------------------
__global__ __launch_bounds__(256) void k_convt2(
    const float* __restrict__ in, const float* __restrict__ w,
    const float* __restrict__ bias, float* __restrict__ out)
{
    __shared__ float in_s[32 * 196];
    __shared__ float w_s[32 * 16 * 16];  // [c][o][ky][kx]
    const int b = blockIdx.x, tid = threadIdx.x;
    for (int e = tid; e < 6272; e += 256) in_s[e] = in[(size_t)b * 6272 + e];
    for (int e = tid; e < 8192; e += 256) w_s[e] = w[e];
    __syncthreads();
    for (int e = tid; e < 12544; e += 256) {
        int o = e / 784, p = e % 784, y = p / 28, xx0 = p % 28;
        float acc = bias[o];
        int ky0 = (y + 1) & 1, kx0 = (xx0 + 1) & 1;
        for (int ky = ky0; ky < 4; ky += 2) {
            int iyn = y + 1 - ky;
            if (iyn < 0) break;
            int iy = iyn >> 1;
            if (iy > 13) continue;
            for (int kx = kx0; kx < 4; kx += 2) {
                int ixn = xx0 + 1 - kx;
                if (ixn < 0) break;
                int ix = ixn >> 1;
                if (ix > 13) continue;
                const float* ip = &in_s[iy * 14 + ix];
                const float* wp = &w_s[o * 16 + ky * 4 + kx];
                float a = 0.f;
                for (int c = 0; c < 32; ++c) a += ip[c * 196] * wp[c * 256];
                acc += a;
            }
        }
        out[(size_t)b * 12544 + e] = fmaxf(acc, 0.f);
    }
}

// ---------------------------------------------------------------------------
// Conv2d 16->8 k3 p1 + ReLU, then Conv2d 8->1 k1 (fused). One block / sample.
// ---------------------------------------------------------------------------
__global__ __launch_bounds__(256) void k_conv23(
    const float* __restrict__ in, const float* __restrict__ w2,
    const float* __restrict__ b2, const float* __restrict__ w3,
    const float* __restrict__ b3, float* __restrict__ out)
{
    __shared__ float in_s[16 * 784];
    __shared__ float w2_s[8 * 16 * 9];
    __shared__ float w3_s[8];
    const int b = blockIdx.x, tid = threadIdx.x;
    for (int e = tid; e < 12544; e += 256) in_s[e] = in[(size_t)b * 12544 + e];
    for (int e = tid; e < 1152; e += 256) w2_s[e] = w2[e];
    if (tid < 8) w3_s[tid] = w3[tid];
    __syncthreads();
    const float bias3 = b3[0];
    for (int p = tid; p < 784; p += 256) {
        int y = p / 28, xx = p % 28;
        float a[8];
        for (int o = 0; o < 8; ++o) a[o] = b2[o];
        for (int c = 0; c < 16; ++c) {
            const float* ip = &in_s[c * 784];
            for (int ky = 0; ky < 3; ++ky) {
                int yy = y + ky - 1;
                if (yy < 0 || yy > 27) continue;
                for (int kx = 0; kx < 3; ++kx) {
                    int x2 = xx + kx - 1;
                    if (x2 < 0 || x2 > 27) continue;
                    float iv = ip[yy * 28 + x2];
                    const float* wp = &w2_s[c * 9 + ky * 3 + kx];
                    for (int o = 0; o < 8; ++o) a[o] += iv * wp[o * 144];
                }
            }
        }
        float r = bias3;
        for (int o = 0; o < 8; ++o) r += fmaxf(a[o], 0.f) * w3_s[o];
        out[(size_t)b * 784 + p] = r;
    }
}

// ---------------------------------------------------------------------------
extern "C" void kernel_launch(void* const* d_in, const int* in_sizes, int n_in,
                              void* d_out, int out_size, void* d_ws, size_t ws_size,
                              hipStream_t stream)
{
    const float* x       = (const float*)d_in[0];
    const float* patch_w = (const float*)d_in[1];
    const float* patch_b = (const float*)d_in[2];
    const float* ln1g    = (const float*)d_in[3];
    const float* ln1b    = (const float*)d_in[4];
    const float* wi      = (const float*)d_in[5];
    const float* bi      = (const float*)d_in[6];
    const float* wo      = (const float*)d_in[7];
    const float* bo      = (const float*)d_in[8];
    const float* ln2g    = (const float*)d_in[9];
    const float* ln2b    = (const float*)d_in[10];
    const float* w1      = (const float*)d_in[11];
    const float* b1      = (const float*)d_in[12];
    const float* w2      = (const float*)d_in[13];
    const float* b2      = (const float*)d_in[14];
    const float* lat_w   = (const float*)d_in[15];
    const float* lat_b   = (const float*)d_in[16];
    const float* memory  = (const float*)d_in[17];
    const float* dec_w   = (const float*)d_in[18];
    const float* dec_b   = (const float*)d_in[19];
    const float* upt1_w  = (const float*)d_in[20];
    const float* upt1_b  = (const float*)d_in[21];
    const float* c1_w    = (const float*)d_in[22];
    const float* c1_b    = (const float*)d_in[23];
    const float* upt2_w  = (const float*)d_in[24];
    const float* upt2_b  = (const float*)d_in[25];
    const float* c2_w    = (const float*)d_in[26];
    const float* c2_b    = (const float*)d_in[27];
    const float* c3_w    = (const float*)d_in[28];
    const float* c3_b    = (const float*)d_in[29];
    float* outp = (float*)d_out;

    float* ws = (float*)d_ws;
    size_t off = 0;
    auto alloc = [&](size_t n) { float* p = ws + off; off += (n + 63) & ~(size_t)63; return p; };
    float* tokens     = alloc((size_t)B_TOT * 1568);
    float* latent     = alloc((size_t)B_TOT * 256);
    float* dots       = alloc((size_t)B_TOT * 4096);
    float* mem_latent = alloc((size_t)B_TOT * 256);
    float* inv_mn     = alloc(4096);
    float* d0         = alloc((size_t)CHUNK * 3136);
    float* d1         = alloc((size_t)CHUNK * 6272);
    float* d2         = alloc((size_t)CHUNK * 6272);
    float* d3         = alloc((size_t)CHUNK * 12544);
    (void)in_sizes; (void)n_in; (void)out_size; (void)ws_size;

    // Encoder
    k_tokens<<<B_TOT, 256, 0, stream>>>(x, patch_w, patch_b, ln1g, ln1b, wi, bi,
                                        wo, bo, ln2g, ln2b, w1, b1, w2, b2, tokens);
    // latent = tokens @ lat_w^T + lat_b   [4096,256]
    k_gemm<<<dim3(256 / 64, B_TOT / 64), 256, 0, stream>>>(tokens, lat_w, lat_b, latent,
                                                           B_TOT, 256, 1568);
    // memory norms + sim + top-k read
    k_mnorm<<<4096, 256, 0, stream>>>(memory, inv_mn);
    k_gemm<<<dim3(4096 / 64, B_TOT / 64), 256, 0, stream>>>(latent, memory, nullptr, dots,
                                                            B_TOT, 4096, 256);
    k_memread<<<B_TOT, 256, 0, stream>>>(latent, dots, inv_mn, memory, mem_latent);

    // Decoder, chunked over batch
    for (int c = 0; c < B_TOT / CHUNK; ++c) {
        const float* ml = mem_latent + (size_t)c * CHUNK * 256;
        k_gemm<<<dim3(3136 / 64, CHUNK / 64), 256, 0, stream>>>(ml, dec_w, dec_b, d0,
                                                                CHUNK, 3136, 256);
        k_convt1<<<CHUNK, 256, 0, stream>>>(d0, upt1_w, upt1_b, d1);
        k_conv1 <<<CHUNK, 256, 0, stream>>>(d1, c1_w, c1_b, d2);
        k_convt2<<<CHUNK, 256, 0, stream>>>(d2, upt2_w, upt2_b, d3);
        k_conv23<<<CHUNK, 256, 0, stream>>>(d3, c2_w, c2_b, c3_w, c3_b,
                                            outp + (size_t)c * CHUNK * 784);
    }
}

// Round 3
// 2454.453 us; speedup vs baseline: 2.8585x; 2.8585x over previous
//
#include <hip/hip_runtime.h>
#include <math.h>

#define B_TOT 4096
#define CHUNK 1024

// ---------------------------------------------------------------------------
// Fused: patch conv (1->32, k4 s4) + 2 transformer blocks. One block / sample.
// ---------------------------------------------------------------------------
__global__ __launch_bounds__(256) void k_tokens(
    const float* __restrict__ x, const float* __restrict__ pw, const float* __restrict__ pb,
    const float* __restrict__ ln1g, const float* __restrict__ ln1b,
    const float* __restrict__ wi, const float* __restrict__ bi,
    const float* __restrict__ wo, const float* __restrict__ bo,
    const float* __restrict__ ln2g, const float* __restrict__ ln2b,
    const float* __restrict__ w1, const float* __restrict__ b1,
    const float* __restrict__ w2, const float* __restrict__ b2,
    float* __restrict__ tokens)
{
    __shared__ float t_s[1568];    // tokens [49][32]
    __shared__ float xn_s[1568];   // LN out / attn out
    __shared__ float w_s[4224];    // staged weights (padded layouts)
    __shared__ float u_s[7200];    // x patch | qkv[49][97] + scores | ff hidden [49][128]
    const int b = blockIdx.x, tid = threadIdx.x;

    for (int e = tid; e < 784; e += 256) u_s[e] = x[(size_t)b * 784 + e];
    for (int e = tid; e < 512; e += 256) { int c = e >> 4, t = e & 15; w_s[c * 17 + t] = pw[e]; }
    __syncthreads();
    for (int e = tid; e < 1568; e += 256) {
        int s = e >> 5, c = e & 31;
        int py = s / 7, px = s % 7;
        float acc = pb[c];
        for (int ky = 0; ky < 4; ++ky)
            for (int kx = 0; kx < 4; ++kx)
                acc += u_s[(py * 4 + ky) * 28 + px * 4 + kx] * w_s[c * 17 + ky * 4 + kx];
        t_s[e] = acc;
    }
    __syncthreads();

    for (int blk = 0; blk < 2; ++blk) {
        if (tid < 49) {
            const float* g = ln1g + blk * 32; const float* bb = ln1b + blk * 32;
            float m = 0.f;
            for (int c = 0; c < 32; ++c) m += t_s[tid * 32 + c];
            m *= (1.f / 32.f);
            float v = 0.f;
            for (int c = 0; c < 32; ++c) { float d = t_s[tid * 32 + c] - m; v += d * d; }
            v *= (1.f / 32.f);
            float rstd = rsqrtf(v + 1e-5f);
            for (int c = 0; c < 32; ++c)
                xn_s[tid * 32 + c] = (t_s[tid * 32 + c] - m) * rstd * g[c] + bb[c];
        }
        __syncthreads();
        for (int e = tid; e < 3072; e += 256) { int j = e >> 5, k = e & 31; w_s[k * 97 + j] = wi[blk * 3072 + e]; }
        __syncthreads();
        for (int e = tid; e < 4704; e += 256) {
            int s = e / 96, j = e % 96;
            float acc = bi[blk * 96 + j];
            for (int k = 0; k < 32; ++k) acc += xn_s[s * 32 + k] * w_s[k * 97 + j];
            u_s[s * 97 + j] = acc;
        }
        __syncthreads();
        float* sc = u_s + 4768;
        for (int h = 0; h < 2; ++h) {
            int qo = h * 16, ko = 32 + h * 16, vo = 64 + h * 16;
            for (int e = tid; e < 2401; e += 256) {
                int i = e / 49, jq = e % 49;
                float acc = 0.f;
                for (int d = 0; d < 16; ++d) acc += u_s[i * 97 + qo + d] * u_s[jq * 97 + ko + d];
                sc[e] = acc * 0.25f;
            }
            __syncthreads();
            if (tid < 49) {
                float mx = -1e30f;
                for (int j = 0; j < 49; ++j) mx = fmaxf(mx, sc[tid * 49 + j]);
                float sum = 0.f;
                for (int j = 0; j < 49; ++j) { float ev = expf(sc[tid * 49 + j] - mx); sc[tid * 49 + j] = ev; sum += ev; }
                float inv = 1.f / sum;
                for (int j = 0; j < 49; ++j) sc[tid * 49 + j] *= inv;
            }
            __syncthreads();
            for (int e = tid; e < 784; e += 256) {
                int i = e >> 4, d = e & 15;
                float acc = 0.f;
                for (int jq = 0; jq < 49; ++jq) acc += sc[i * 49 + jq] * u_s[jq * 97 + vo + d];
                xn_s[i * 32 + qo + d] = acc;
            }
            __syncthreads();
        }
        for (int e = tid; e < 1024; e += 256) { int c = e >> 5, ei = e & 31; w_s[ei * 33 + c] = wo[blk * 1024 + e]; }
        __syncthreads();
        for (int e = tid; e < 1568; e += 256) {
            int s = e >> 5, c = e & 31;
            float acc = bo[blk * 32 + c];
            for (int k = 0; k < 32; ++k) acc += xn_s[s * 32 + k] * w_s[k * 33 + c];
            t_s[e] += acc;
        }
        __syncthreads();
        if (tid < 49) {
            const float* g = ln2g + blk * 32; const float* bb = ln2b + blk * 32;
            float m = 0.f;
            for (int c = 0; c < 32; ++c) m += t_s[tid * 32 + c];
            m *= (1.f / 32.f);
            float v = 0.f;
            for (int c = 0; c < 32; ++c) { float d = t_s[tid * 32 + c] - m; v += d * d; }
            v *= (1.f / 32.f);
            float rstd = rsqrtf(v + 1e-5f);
            for (int c = 0; c < 32; ++c)
                xn_s[tid * 32 + c] = (t_s[tid * 32 + c] - m) * rstd * g[c] + bb[c];
        }
        __syncthreads();
        for (int e = tid; e < 4096; e += 256) { int j = e >> 5, k = e & 31; w_s[k * 129 + j] = w1[blk * 4096 + e]; }
        __syncthreads();
        for (int e = tid; e < 6272; e += 256) {
            int s = e >> 7, j = e & 127;
            float acc = b1[blk * 128 + j];
            for (int k = 0; k < 32; ++k) acc += xn_s[s * 32 + k] * w_s[k * 129 + j];
            acc = 0.5f * acc * (1.f + erff(acc * 0.7071067811865476f));
            u_s[e] = acc;
        }
        __syncthreads();
        for (int e = tid; e < 4096; e += 256) { int c = e >> 7, k = e & 127; w_s[k * 33 + c] = w2[blk * 4096 + e]; }
        __syncthreads();
        for (int e = tid; e < 1568; e += 256) {
            int s = e >> 5, c = e & 31;
            float acc = b2[blk * 32 + c];
            for (int k = 0; k < 128; ++k) acc += u_s[s * 128 + k] * w_s[k * 33 + c];
            t_s[e] += acc;
        }
        __syncthreads();
    }
    for (int e = tid; e < 1568; e += 256) tokens[(size_t)b * 1568 + e] = t_s[e];
}

// ---------------------------------------------------------------------------
// C[M,N] = A[M,K] @ B[N,K]^T (+bias). 64x64 tile, BK=16, 4x4 microtile.
// ---------------------------------------------------------------------------
__global__ __launch_bounds__(256) void k_gemm(
    const float* __restrict__ A, const float* __restrict__ Bm,
    const float* __restrict__ bias, float* __restrict__ C,
    int M, int N, int K)
{
    __shared__ float As[16 * 68];
    __shared__ float Bs[16 * 68];
    const int n0 = blockIdx.x * 64, m0 = blockIdx.y * 64;
    const int tid = threadIdx.x;
    const int tx = tid & 15, ty = tid >> 4;
    float acc[4][4] = {{0.f}};
    for (int k0 = 0; k0 < K; k0 += 16) {
        for (int l = 0; l < 4; ++l) {
            int idx = tid + l * 256;
            int m = idx >> 4, k = idx & 15;
            As[k * 68 + m] = A[(size_t)(m0 + m) * K + k0 + k];
            Bs[k * 68 + m] = Bm[(size_t)(n0 + m) * K + k0 + k];
        }
        __syncthreads();
        for (int k = 0; k < 16; ++k) {
            float4 av = *(const float4*)&As[k * 68 + ty * 4];
            float4 bv = *(const float4*)&Bs[k * 68 + tx * 4];
            float a4[4] = {av.x, av.y, av.z, av.w};
            float b4[4] = {bv.x, bv.y, bv.z, bv.w};
            for (int i = 0; i < 4; ++i)
                for (int j = 0; j < 4; ++j)
                    acc[i][j] += a4[i] * b4[j];
        }
        __syncthreads();
    }
    for (int i = 0; i < 4; ++i) {
        int m = m0 + ty * 4 + i;
        for (int j = 0; j < 4; ++j) {
            int n = n0 + tx * 4 + j;
            float v = acc[i][j] + (bias ? bias[n] : 0.f);
            C[(size_t)m * N + n] = v;
        }
    }
}

// ---------------------------------------------------------------------------
__global__ __launch_bounds__(256) void k_mnorm(const float* __restrict__ mem, float* __restrict__ inv_norm)
{
    __shared__ float red[256];
    const int row = blockIdx.x, tid = threadIdx.x;
    float v = mem[(size_t)row * 256 + tid];
    red[tid] = v * v;
    __syncthreads();
    for (int s = 128; s > 0; s >>= 1) {
        if (tid < s) red[tid] += red[tid + s];
        __syncthreads();
    }
    if (tid == 0) inv_norm[row] = 1.f / fmaxf(sqrtf(red[0]), 1e-12f);
}

// ---------------------------------------------------------------------------
__global__ __launch_bounds__(256) void k_memread(
    const float* __restrict__ latent, const float* __restrict__ dots,
    const float* __restrict__ inv_mn, const float* __restrict__ mem,
    float* __restrict__ out)
{
    __shared__ float red[256];
    __shared__ int   redi[256];
    __shared__ float inv_x_s;
    const int b = blockIdx.x, tid = threadIdx.x;
    float lx = latent[(size_t)b * 256 + tid];
    red[tid] = lx * lx;
    __syncthreads();
    for (int s = 128; s > 0; s >>= 1) {
        if (tid < s) red[tid] += red[tid + s];
        __syncthreads();
    }
    if (tid == 0) inv_x_s = 1.f / fmaxf(sqrtf(red[0]), 1e-12f);
    __syncthreads();
    const float inv_x = inv_x_s;

    float vals[16];
    for (int j = 0; j < 16; ++j) {
        int m = tid + j * 256;
        vals[j] = dots[(size_t)b * 4096 + m] * inv_mn[m] * inv_x;
    }
    float tv[10]; int ti[10];
    for (int t = 0; t < 10; ++t) {
        float bv = -1e30f; int bidx = 0x7fffffff;
        for (int j = 0; j < 16; ++j) {
            int m = tid + j * 256;
            float v = vals[j];
            if (v > bv || (v == bv && m < bidx)) { bv = v; bidx = m; }
        }
        red[tid] = bv; redi[tid] = bidx;
        __syncthreads();
        for (int s = 128; s > 0; s >>= 1) {
            if (tid < s) {
                float v2 = red[tid + s]; int i2 = redi[tid + s];
                if (v2 > red[tid] || (v2 == red[tid] && i2 < redi[tid])) { red[tid] = v2; redi[tid] = i2; }
            }
            __syncthreads();
        }
        int sel = redi[0];
        tv[t] = red[0]; ti[t] = sel;
        if ((sel & 255) == tid) vals[sel >> 8] = -1e30f;
        __syncthreads();
    }
    float w[10], wsum = 0.f;
    for (int t = 0; t < 10; ++t) { w[t] = expf(tv[t] - tv[0]); wsum += w[t]; }
    float inv_ws = 1.f / wsum;
    float acc = 0.f;
    for (int t = 0; t < 10; ++t) acc += (w[t] * inv_ws) * mem[(size_t)ti[t] * 256 + tid];
    out[(size_t)b * 256 + tid] = acc;
}

// ---------------------------------------------------------------------------
// Weight repack for SGPR-friendly decoder conv layouts.
//   pk1[c64][q4][tap4][o32]  from upt1_w [64][32][4][4]   (ConvT k4s2 subpixel)
//   pk2[c32][tap9][o32]      from c1_w   [32][32][3][3]
//   pk3[c32][q4][tap4][o16]  from upt2_w [32][16][4][4]
//   pk4[c16][tap9][o8]       from c2_w   [8][16][3][3]
// ---------------------------------------------------------------------------
__global__ __launch_bounds__(256) void k_pack(
    const float* __restrict__ wt1, const float* __restrict__ wc1,
    const float* __restrict__ wt2, const float* __restrict__ wc2,
    float* __restrict__ pk1, float* __restrict__ pk2,
    float* __restrict__ pk3, float* __restrict__ pk4)
{
    int i = blockIdx.x * 256 + threadIdx.x;
    if (i < 32768) {
        int o = i & 31, t = (i >> 5) & 3, q = (i >> 7) & 3, c = i >> 9;
        int wy = t >> 1, wx = t & 1, py = q >> 1, px = q & 1;
        int ky = 3 - py - 2 * wy, kx = 3 - px - 2 * wx;
        pk1[i] = wt1[((c * 32 + o) * 4 + ky) * 4 + kx];
    }
    if (i < 9216) {
        int o = i & 31, tap = (i >> 5) % 9, c = i / 288;
        pk2[i] = wc1[(o * 32 + c) * 9 + tap];
    }
    if (i < 8192) {
        int o = i & 15, t = (i >> 4) & 3, q = (i >> 6) & 3, c = i >> 8;
        int wy = t >> 1, wx = t & 1, py = q >> 1, px = q & 1;
        int ky = 3 - py - 2 * wy, kx = 3 - px - 2 * wx;
        pk3[i] = wt2[((c * 16 + o) * 4 + ky) * 4 + kx];
    }
    if (i < 1152) {
        int o = i & 7, tap = (i >> 3) % 9, c = i / 72;
        pk4[i] = wc2[(o * 16 + c) * 9 + tap];
    }
}

// ---------------------------------------------------------------------------
// ConvTranspose2d 64->32 k4 s2 p1, 7x7 -> 14x14, ReLU. 1 sample/block.
// wave = output parity q; lane owns 1 parity-pixel x all 32 o (SGPR weights).
// ---------------------------------------------------------------------------
__global__ __launch_bounds__(256) void k_convt1(
    const float* __restrict__ in, const float* __restrict__ pk1,
    const float* __restrict__ bias, float* __restrict__ out)
{
    __shared__ float P[64 * 108];   // [c][9 rows][12 cols], zero-padded
    const int b = blockIdx.x, tid = threadIdx.x;
    for (int e = tid; e < 6912; e += 256) P[e] = 0.f;
    __syncthreads();
    for (int e = tid; e < 3136; e += 256) {
        int c = e / 49, p = e % 49;
        P[c * 108 + (p / 7 + 1) * 12 + (p % 7 + 1)] = in[(size_t)b * 3136 + e];
    }
    __syncthreads();

    const int q  = __builtin_amdgcn_readfirstlane(tid >> 6);
    const int py = q >> 1, px = q & 1;
    const int lane = tid & 63;
    const bool active = lane < 56;
    int ty = lane >> 3, tx = lane & 7;
    if (!active) { ty = 0; tx = 0; }
    const bool do_store = active && (tx < 7);
    const int rbase = ty + py, cbase = tx + px;

    float acc[32];
    #pragma unroll
    for (int o = 0; o < 32; ++o) acc[o] = 0.f;

    for (int c = 0; c < 64; ++c) {
        const float* Pc = &P[c * 108 + rbase * 12 + cbase];
        float vin[4];
        vin[0] = Pc[0]; vin[1] = Pc[1]; vin[2] = Pc[12]; vin[3] = Pc[13];
        const float* wq = pk1 + (size_t)((c * 4 + q) * 4) * 32;
        #pragma unroll
        for (int t = 0; t < 4; ++t) {
            const float* wt = wq + t * 32;
            float v = vin[t];
            #pragma unroll
            for (int o = 0; o < 32; ++o) acc[o] = fmaf(v, wt[o], acc[o]);
        }
    }
    if (do_store) {
        const int y = 2 * ty + py, xx = 2 * tx + px;
        float* op = out + (size_t)b * 6272 + y * 14 + xx;
        #pragma unroll
        for (int o = 0; o < 32; ++o) op[o * 196] = fmaxf(acc[o] + bias[o], 0.f);
    }
}

// ---------------------------------------------------------------------------
// Conv2d 32->32 k3 p1, 14x14, ReLU. 2 samples/block.
// wave = (o-half, sample); lane owns 4 pixels x 16 o (SGPR weights).
// ---------------------------------------------------------------------------
__global__ __launch_bounds__(256) void k_conv1(
    const float* __restrict__ in, const float* __restrict__ pk2,
    const float* __restrict__ bias, float* __restrict__ out)
{
    __shared__ float P[8208];   // [s2][c16][16 rows][16 cols] + float4 overread pad
    const int tid = threadIdx.x;
    const int wv = __builtin_amdgcn_readfirstlane(tid >> 6);
    const int og = wv & 1, s = wv >> 1;
    const int lane = tid & 63;
    const bool active = lane < 56;
    int row = lane >> 2, tx0 = (lane & 3) * 4;
    if (!active) { row = 0; tx0 = 0; }
    const size_t b = (size_t)blockIdx.x * 2 + s;

    float acc[4][16];
    #pragma unroll
    for (int i = 0; i < 4; ++i)
        #pragma unroll
        for (int o = 0; o < 16; ++o) acc[i][o] = 0.f;

    for (int cc = 0; cc < 32; cc += 16) {
        __syncthreads();
        for (int e = tid; e < 8208; e += 256) P[e] = 0.f;
        __syncthreads();
        for (int e = tid; e < 6272; e += 256) {
            int si = e / 3136, rem = e - si * 3136;
            int c = rem / 196, p = rem % 196;
            P[((si * 16 + c) * 16 + p / 14 + 1) * 16 + (p % 14 + 1)] =
                in[((size_t)(blockIdx.x * 2 + si) * 32 + cc + c) * 196 + p];
        }
        __syncthreads();
        for (int cl = 0; cl < 16; ++cl) {
            const float* Pb = &P[((s * 16 + cl) * 16 + row) * 16 + tx0];
            float rowb[3][8];
            #pragma unroll
            for (int ky = 0; ky < 3; ++ky) {
                float4 a = *(const float4*)&Pb[ky * 16];
                float4 bq = *(const float4*)&Pb[ky * 16 + 4];
                rowb[ky][0] = a.x; rowb[ky][1] = a.y; rowb[ky][2] = a.z; rowb[ky][3] = a.w;
                rowb[ky][4] = bq.x; rowb[ky][5] = bq.y; rowb[ky][6] = bq.z; rowb[ky][7] = bq.w;
            }
            const float* wbase = pk2 + (size_t)(cc + cl) * 288 + og * 16;
            #pragma unroll
            for (int ky = 0; ky < 3; ++ky) {
                #pragma unroll
                for (int kx = 0; kx < 3; ++kx) {
                    const float* wt = wbase + (ky * 3 + kx) * 32;
                    #pragma unroll
                    for (int o = 0; o < 16; ++o) {
                        float w = wt[o];
                        #pragma unroll
                        for (int i = 0; i < 4; ++i)
                            acc[i][o] = fmaf(rowb[ky][i + kx], w, acc[i][o]);
                    }
                }
            }
        }
    }
    if (active) {
        #pragma unroll
        for (int o = 0; o < 16; ++o) {
            int oo = og * 16 + o;
            float bo = bias[oo];
            #pragma unroll
            for (int i = 0; i < 4; ++i) {
                int xx = tx0 + i;
                if (xx < 14)
                    out[(b * 32 + oo) * 196 + row * 14 + xx] = fmaxf(acc[i][o] + bo, 0.f);
            }
        }
    }
}

// ---------------------------------------------------------------------------
// ConvTranspose2d 32->16 k4 s2 p1, 14x14 -> 28x28, ReLU. 1 sample/block.
// wave = parity q; lane owns 4 parity-pixels x 16 o (SGPR weights).
// ---------------------------------------------------------------------------
__global__ __launch_bounds__(256) void k_convt2(
    const float* __restrict__ in, const float* __restrict__ pk3,
    const float* __restrict__ bias, float* __restrict__ out)
{
    __shared__ float P[32 * 320];   // [c][16 rows][20 cols], zero-padded
    const int b = blockIdx.x, tid = threadIdx.x;
    for (int e = tid; e < 10240; e += 256) P[e] = 0.f;
    __syncthreads();
    for (int e = tid; e < 6272; e += 256) {
        int c = e / 196, p = e % 196;
        P[c * 320 + (p / 14 + 1) * 20 + (p % 14 + 1)] = in[(size_t)b * 6272 + e];
    }
    __syncthreads();

    const int q  = __builtin_amdgcn_readfirstlane(tid >> 6);
    const int py = q >> 1, px = q & 1;
    const int lane = tid & 63;
    const bool active = lane < 56;
    int ty = lane >> 2, tx0 = (lane & 3) * 4;
    if (!active) { ty = 0; tx0 = 0; }
    const int rbase = ty + py;

    float acc[4][16];
    #pragma unroll
    for (int i = 0; i < 4; ++i)
        #pragma unroll
        for (int o = 0; o < 16; ++o) acc[i][o] = 0.f;

    for (int c = 0; c < 32; ++c) {
        const float* Pb = &P[c * 320 + rbase * 20 + tx0];
        float raw[2][8];
        #pragma unroll
        for (int r2 = 0; r2 < 2; ++r2) {
            float4 a = *(const float4*)&Pb[r2 * 20];
            float4 bq = *(const float4*)&Pb[r2 * 20 + 4];
            raw[r2][0] = a.x; raw[r2][1] = a.y; raw[r2][2] = a.z; raw[r2][3] = a.w;
            raw[r2][4] = bq.x; raw[r2][5] = bq.y; raw[r2][6] = bq.z; raw[r2][7] = bq.w;
        }
        float rs[2][5];
        #pragma unroll
        for (int r2 = 0; r2 < 2; ++r2)
            #pragma unroll
            for (int j = 0; j < 5; ++j) rs[r2][j] = px ? raw[r2][j + 1] : raw[r2][j];
        const float* wq = pk3 + (size_t)((c * 4 + q) * 4) * 16;
        #pragma unroll
        for (int t = 0; t < 4; ++t) {
            int wy = t >> 1, wx = t & 1;
            const float* wt = wq + t * 16;
            #pragma unroll
            for (int o = 0; o < 16; ++o) {
                float w = wt[o];
                #pragma unroll
                for (int i = 0; i < 4; ++i)
                    acc[i][o] = fmaf(rs[wy][i + wx], w, acc[i][o]);
            }
        }
    }
    if (active) {
        const int y = 2 * ty + py;
        #pragma unroll
        for (int i = 0; i < 4; ++i) {
            int xt = tx0 + i;
            if (xt < 14) {
                int xx = 2 * xt + px;
                #pragma unroll
                for (int o = 0; o < 16; ++o)
                    out[((size_t)b * 16 + o) * 784 + y * 28 + xx] = fmaxf(acc[i][o] + bias[o], 0.f);
            }
        }
    }
}

// ---------------------------------------------------------------------------
// Conv2d 16->8 k3 p1 + ReLU fused with Conv2d 8->1 k1. 1 sample/block.
// lane owns 4 pixels x all 8 o (SGPR weights).
// ---------------------------------------------------------------------------
__global__ __launch_bounds__(256) void k_conv23(
    const float* __restrict__ in, const float* __restrict__ pk4,
    const float* __restrict__ b2, const float* __restrict__ w3,
    const float* __restrict__ b3, float* __restrict__ out)
{
    __shared__ float P[8 * 960];   // [c8][30 rows][32 cols], zero-padded
    const int b = blockIdx.x, tid = threadIdx.x;
    const bool active = tid < 196;
    int row = tid / 7, tx0 = (tid % 7) * 4;
    if (!active) { row = 0; tx0 = 0; }

    float acc[4][8];
    #pragma unroll
    for (int i = 0; i < 4; ++i)
        #pragma unroll
        for (int o = 0; o < 8; ++o) acc[i][o] = 0.f;

    for (int cc = 0; cc < 16; cc += 8) {
        __syncthreads();
        for (int e = tid; e < 7680; e += 256) P[e] = 0.f;
        __syncthreads();
        for (int e = tid; e < 6272; e += 256) {
            int c = e / 784, p = e % 784;
            P[(c * 30 + p / 28 + 1) * 32 + (p % 28 + 1)] =
                in[(size_t)b * 12544 + (cc + c) * 784 + p];
        }
        __syncthreads();
        for (int cl = 0; cl < 8; ++cl) {
            const float* Pb = &P[(cl * 30 + row) * 32 + tx0];
            const float* wb = pk4 + (size_t)(cc + cl) * 72;
            #pragma unroll
            for (int ky = 0; ky < 3; ++ky) {
                float4 a = *(const float4*)&Pb[ky * 32];
                float4 bq = *(const float4*)&Pb[ky * 32 + 4];
                float rowb[8] = {a.x, a.y, a.z, a.w, bq.x, bq.y, bq.z, bq.w};
                #pragma unroll
                for (int kx = 0; kx < 3; ++kx) {
                    const float* wt = wb + (ky * 3 + kx) * 8;
                    #pragma unroll
                    for (int o = 0; o < 8; ++o) {
                        float w = wt[o];
                        #pragma unroll
                        for (int i = 0; i < 4; ++i)
                            acc[i][o] = fmaf(rowb[i + kx], w, acc[i][o]);
                    }
                }
            }
        }
    }
    if (active) {
        const float bias3 = b3[0];
        #pragma unroll
        for (int i = 0; i < 4; ++i) {
            float r = bias3;
            #pragma unroll
            for (int o = 0; o < 8; ++o) r += fmaxf(acc[i][o] + b2[o], 0.f) * w3[o];
            out[(size_t)b * 784 + row * 28 + tx0 + i] = r;
        }
    }
}

// ---------------------------------------------------------------------------
extern "C" void kernel_launch(void* const* d_in, const int* in_sizes, int n_in,
                              void* d_out, int out_size, void* d_ws, size_t ws_size,
                              hipStream_t stream)
{
    const float* x       = (const float*)d_in[0];
    const float* patch_w = (const float*)d_in[1];
    const float* patch_b = (const float*)d_in[2];
    const float* ln1g    = (const float*)d_in[3];
    const float* ln1b    = (const float*)d_in[4];
    const float* wi      = (const float*)d_in[5];
    const float* bi      = (const float*)d_in[6];
    const float* wo      = (const float*)d_in[7];
    const float* bo      = (const float*)d_in[8];
    const float* ln2g    = (const float*)d_in[9];
    const float* ln2b    = (const float*)d_in[10];
    const float* w1      = (const float*)d_in[11];
    const float* b1      = (const float*)d_in[12];
    const float* w2      = (const float*)d_in[13];
    const float* b2      = (const float*)d_in[14];
    const float* lat_w   = (const float*)d_in[15];
    const float* lat_b   = (const float*)d_in[16];
    const float* memory  = (const float*)d_in[17];
    const float* dec_w   = (const float*)d_in[18];
    const float* dec_b   = (const float*)d_in[19];
    const float* upt1_w  = (const float*)d_in[20];
    const float* upt1_b  = (const float*)d_in[21];
    const float* c1_w    = (const float*)d_in[22];
    const float* c1_b    = (const float*)d_in[23];
    const float* upt2_w  = (const float*)d_in[24];
    const float* upt2_b  = (const float*)d_in[25];
    const float* c2_w    = (const float*)d_in[26];
    const float* c2_b    = (const float*)d_in[27];
    const float* c3_w    = (const float*)d_in[28];
    const float* c3_b    = (const float*)d_in[29];
    float* outp = (float*)d_out;

    float* ws = (float*)d_ws;
    size_t off = 0;
    auto alloc = [&](size_t n) { float* p = ws + off; off += (n + 63) & ~(size_t)63; return p; };
    float* tokens     = alloc((size_t)B_TOT * 1568);
    float* latent     = alloc((size_t)B_TOT * 256);
    float* dots       = alloc((size_t)B_TOT * 4096);
    float* mem_latent = alloc((size_t)B_TOT * 256);
    float* inv_mn     = alloc(4096);
    float* pk1        = alloc(32768);
    float* pk2        = alloc(9216);
    float* pk3        = alloc(8192);
    float* pk4        = alloc(1152);
    float* d0         = alloc((size_t)CHUNK * 3136);
    float* d1         = alloc((size_t)CHUNK * 6272);
    float* d2         = alloc((size_t)CHUNK * 6272);
    float* d3         = alloc((size_t)CHUNK * 12544);
    (void)in_sizes; (void)n_in; (void)out_size; (void)ws_size;

    // Weight repack for decoder convs
    k_pack<<<128, 256, 0, stream>>>(upt1_w, c1_w, upt2_w, c2_w, pk1, pk2, pk3, pk4);

    // Encoder
    k_tokens<<<B_TOT, 256, 0, stream>>>(x, patch_w, patch_b, ln1g, ln1b, wi, bi,
                                        wo, bo, ln2g, ln2b, w1, b1, w2, b2, tokens);
    k_gemm<<<dim3(256 / 64, B_TOT / 64), 256, 0, stream>>>(tokens, lat_w, lat_b, latent,
                                                           B_TOT, 256, 1568);
    k_mnorm<<<4096, 256, 0, stream>>>(memory, inv_mn);
    k_gemm<<<dim3(4096 / 64, B_TOT / 64), 256, 0, stream>>>(latent, memory, nullptr, dots,
                                                            B_TOT, 4096, 256);
    k_memread<<<B_TOT, 256, 0, stream>>>(latent, dots, inv_mn, memory, mem_latent);

    // Decoder, chunked over batch
    for (int c = 0; c < B_TOT / CHUNK; ++c) {
        const float* ml = mem_latent + (size_t)c * CHUNK * 256;
        k_gemm<<<dim3(3136 / 64, CHUNK / 64), 256, 0, stream>>>(ml, dec_w, dec_b, d0,
                                                                CHUNK, 3136, 256);
        k_convt1<<<CHUNK, 256, 0, stream>>>(d0, pk1, upt1_b, d1);
        k_conv1 <<<CHUNK / 2, 256, 0, stream>>>(d1, pk2, c1_b, d2);
        k_convt2<<<CHUNK, 256, 0, stream>>>(d2, pk3, upt2_b, d3);
        k_conv23<<<CHUNK, 256, 0, stream>>>(d3, pk4, c2_b, c3_w, c3_b,
                                            outp + (size_t)c * CHUNK * 784);
    }
}

// Round 4
// 2170.171 us; speedup vs baseline: 3.2330x; 1.1310x over previous
//
#include <hip/hip_runtime.h>
#include <math.h>

#define B_TOT 4096
#define CHUNK 1024
#define TOKS 34   // LDS row stride for k/v rows (2s mod 32 -> 2-way = free)

// ---------------------------------------------------------------------------
// Fused: patch conv (1->32, k4 s4) + 2 transformer blocks.
// One WAVE per sample, one LANE per token. Activations in registers,
// weights via wave-uniform scalar loads (VGPR x SGPR fma), K/V rows in LDS
// read as wave-uniform broadcasts. Online softmax, both heads per j.
// ---------------------------------------------------------------------------
__global__ __launch_bounds__(256) void k_tokens(
    const float* __restrict__ x, const float* __restrict__ pw, const float* __restrict__ pb,
    const float* __restrict__ ln1g, const float* __restrict__ ln1b,
    const float* __restrict__ wi, const float* __restrict__ bi,
    const float* __restrict__ wo, const float* __restrict__ bo,
    const float* __restrict__ ln2g, const float* __restrict__ ln2b,
    const float* __restrict__ w1, const float* __restrict__ fb1,
    const float* __restrict__ w2t, const float* __restrict__ fb2,
    float* __restrict__ tokens)
{
    __shared__ __align__(16) float L[4 * 3332];   // per wave: k[49][34] + v[49][34]
    const int tid = threadIdx.x;
    const int wv = tid >> 6, lane = tid & 63;
    const int b = blockIdx.x * 4 + wv;
    float* kb = L + wv * 3332;
    float* vb = kb + 1666;
    const bool is_tok = lane < 49;
    const int s = is_tok ? lane : 48;   // idle lanes mirror token 48 (never store)
    const int py = s / 7, px = s % 7;

    // stage this sample's x (784 floats) coalesced into kb region (reused later)
    for (int e = lane; e < 784; e += 64) kb[e] = x[(size_t)b * 784 + e];
    __syncthreads();

    // patch embed -> t[32] in registers
    float xv[16];
    #pragma unroll
    for (int t2 = 0; t2 < 16; ++t2)
        xv[t2] = kb[(py * 4 + (t2 >> 2)) * 28 + px * 4 + (t2 & 3)];
    float t[32];
    #pragma unroll
    for (int c = 0; c < 32; ++c) {
        float a = pb[c];
        const float* wr = pw + c * 16;
        #pragma unroll
        for (int t2 = 0; t2 < 16; ++t2) a = fmaf(xv[t2], wr[t2], a);
        t[c] = a;
    }

    for (int blk = 0; blk < 2; ++blk) {
        const float* wib = wi + blk * 3072;
        const float* bib = bi + blk * 96;

        // ---- LN1 (all in-lane)
        float mu = 0.f;
        #pragma unroll
        for (int c = 0; c < 32; ++c) mu += t[c];
        mu *= 0.03125f;
        float var = 0.f;
        #pragma unroll
        for (int c = 0; c < 32; ++c) { float d = t[c] - mu; var = fmaf(d, d, var); }
        float rstd = rsqrtf(var * 0.03125f + 1e-5f);
        float xn[32];
        #pragma unroll
        for (int c = 0; c < 32; ++c)
            xn[c] = (t[c] - mu) * rstd * ln1g[blk * 32 + c] + ln1b[blk * 32 + c];

        __syncthreads();   // all prior LDS reads (x patch / prev attention) done

        // ---- k rows -> LDS
        for (int d = 0; d < 32; ++d) {
            const float* wr = wib + (32 + d) * 32;
            float a = bib[32 + d];
            #pragma unroll
            for (int c = 0; c < 32; ++c) a = fmaf(xn[c], wr[c], a);
            if (is_tok) kb[s * TOKS + d] = a;
        }
        // ---- v rows -> LDS
        for (int d = 0; d < 32; ++d) {
            const float* wr = wib + (64 + d) * 32;
            float a = bib[64 + d];
            #pragma unroll
            for (int c = 0; c < 32; ++c) a = fmaf(xn[c], wr[c], a);
            if (is_tok) vb[s * TOKS + d] = a;
        }
        // ---- q -> registers
        float q[32];
        #pragma unroll
        for (int d = 0; d < 32; ++d) {
            const float* wr = wib + d * 32;
            float a = bib[d];
            #pragma unroll
            for (int c = 0; c < 32; ++c) a = fmaf(xn[c], wr[c], a);
            q[d] = a;
        }
        __syncthreads();   // k/v visible

        // ---- attention: online softmax, both heads per j
        float o[32];
        #pragma unroll
        for (int d = 0; d < 32; ++d) o[d] = 0.f;
        float m0 = -1e30f, l0 = 0.f, m1 = -1e30f, l1 = 0.f;
        for (int j = 0; j < 49; ++j) {
            const float* kr = &kb[j * TOKS];
            const float* vr = &vb[j * TOKS];
            float s0 = 0.f, s1 = 0.f;
            #pragma unroll
            for (int d2 = 0; d2 < 8; ++d2) {
                float2 ka = *(const float2*)&kr[2 * d2];
                s0 = fmaf(q[2 * d2], ka.x, s0);
                s0 = fmaf(q[2 * d2 + 1], ka.y, s0);
                float2 kc = *(const float2*)&kr[16 + 2 * d2];
                s1 = fmaf(q[16 + 2 * d2], kc.x, s1);
                s1 = fmaf(q[16 + 2 * d2 + 1], kc.y, s1);
            }
            s0 *= 0.25f; s1 *= 0.25f;
            float m0n = fmaxf(m0, s0), m1n = fmaxf(m1, s1);
            float al0 = expf(m0 - m0n), p0 = expf(s0 - m0n);
            float al1 = expf(m1 - m1n), p1 = expf(s1 - m1n);
            l0 = fmaf(l0, al0, p0); l1 = fmaf(l1, al1, p1);
            m0 = m0n; m1 = m1n;
            #pragma unroll
            for (int d2 = 0; d2 < 8; ++d2) {
                float2 va = *(const float2*)&vr[2 * d2];
                o[2 * d2]     = fmaf(o[2 * d2],     al0, p0 * va.x);
                o[2 * d2 + 1] = fmaf(o[2 * d2 + 1], al0, p0 * va.y);
                float2 vc = *(const float2*)&vr[16 + 2 * d2];
                o[16 + 2 * d2]     = fmaf(o[16 + 2 * d2],     al1, p1 * vc.x);
                o[16 + 2 * d2 + 1] = fmaf(o[16 + 2 * d2 + 1], al1, p1 * vc.y);
            }
        }
        float il0 = 1.f / l0, il1 = 1.f / l1;
        #pragma unroll
        for (int d = 0; d < 16; ++d) { o[d] *= il0; o[16 + d] *= il1; }

        // ---- out-proj + residual
        #pragma unroll
        for (int c = 0; c < 32; ++c) {
            const float* wr = wo + blk * 1024 + c * 32;
            float a = bo[blk * 32 + c];
            #pragma unroll
            for (int k2 = 0; k2 < 32; ++k2) a = fmaf(o[k2], wr[k2], a);
            t[c] += a;
        }

        // ---- LN2
        mu = 0.f;
        #pragma unroll
        for (int c = 0; c < 32; ++c) mu += t[c];
        mu *= 0.03125f;
        var = 0.f;
        #pragma unroll
        for (int c = 0; c < 32; ++c) { float d = t[c] - mu; var = fmaf(d, d, var); }
        rstd = rsqrtf(var * 0.03125f + 1e-5f);
        #pragma unroll
        for (int c = 0; c < 32; ++c)
            xn[c] = (t[c] - mu) * rstd * ln2g[blk * 32 + c] + ln2b[blk * 32 + c];

        // ---- FF (hidden value consumed immediately; never materialize 128)
        #pragma unroll 2
        for (int j = 0; j < 128; ++j) {
            const float* wr = w1 + blk * 4096 + j * 32;
            float h = fb1[blk * 128 + j];
            #pragma unroll
            for (int c = 0; c < 32; ++c) h = fmaf(xn[c], wr[c], h);
            h = 0.5f * h * (1.f + erff(h * 0.7071067811865476f));
            const float* w2r = w2t + blk * 4096 + j * 32;
            #pragma unroll
            for (int c = 0; c < 32; ++c) t[c] = fmaf(h, w2r[c], t[c]);
        }
        #pragma unroll
        for (int c = 0; c < 32; ++c) t[c] += fb2[blk * 32 + c];
    }

    if (is_tok) {
        float* op = tokens + (size_t)b * 1568 + s * 32;
        #pragma unroll
        for (int c = 0; c < 32; c += 4) {
            float4 vv = make_float4(t[c], t[c + 1], t[c + 2], t[c + 3]);
            *(float4*)&op[c] = vv;
        }
    }
}

// ---------------------------------------------------------------------------
// C[M,N] = A[M,K] @ B[N,K]^T (+bias). 64x64 tile, BK=16, 4x4 microtile.
// ---------------------------------------------------------------------------
__global__ __launch_bounds__(256) void k_gemm(
    const float* __restrict__ A, const float* __restrict__ Bm,
    const float* __restrict__ bias, float* __restrict__ C,
    int M, int N, int K)
{
    __shared__ float As[16 * 68];
    __shared__ float Bs[16 * 68];
    const int n0 = blockIdx.x * 64, m0 = blockIdx.y * 64;
    const int tid = threadIdx.x;
    const int tx = tid & 15, ty = tid >> 4;
    float acc[4][4] = {{0.f}};
    for (int k0 = 0; k0 < K; k0 += 16) {
        for (int l = 0; l < 4; ++l) {
            int idx = tid + l * 256;
            int m = idx >> 4, k = idx & 15;
            As[k * 68 + m] = A[(size_t)(m0 + m) * K + k0 + k];
            Bs[k * 68 + m] = Bm[(size_t)(n0 + m) * K + k0 + k];
        }
        __syncthreads();
        for (int k = 0; k < 16; ++k) {
            float4 av = *(const float4*)&As[k * 68 + ty * 4];
            float4 bv = *(const float4*)&Bs[k * 68 + tx * 4];
            float a4[4] = {av.x, av.y, av.z, av.w};
            float b4[4] = {bv.x, bv.y, bv.z, bv.w};
            for (int i = 0; i < 4; ++i)
                for (int j = 0; j < 4; ++j)
                    acc[i][j] += a4[i] * b4[j];
        }
        __syncthreads();
    }
    for (int i = 0; i < 4; ++i) {
        int m = m0 + ty * 4 + i;
        for (int j = 0; j < 4; ++j) {
            int n = n0 + tx * 4 + j;
            float v = acc[i][j] + (bias ? bias[n] : 0.f);
            C[(size_t)m * N + n] = v;
        }
    }
}

// ---------------------------------------------------------------------------
__global__ __launch_bounds__(256) void k_mnorm(const float* __restrict__ mem, float* __restrict__ inv_norm)
{
    __shared__ float red[256];
    const int row = blockIdx.x, tid = threadIdx.x;
    float v = mem[(size_t)row * 256 + tid];
    red[tid] = v * v;
    __syncthreads();
    for (int s = 128; s > 0; s >>= 1) {
        if (tid < s) red[tid] += red[tid + s];
        __syncthreads();
    }
    if (tid == 0) inv_norm[row] = 1.f / fmaxf(sqrtf(red[0]), 1e-12f);
}

// ---------------------------------------------------------------------------
__global__ __launch_bounds__(256) void k_memread(
    const float* __restrict__ latent, const float* __restrict__ dots,
    const float* __restrict__ inv_mn, const float* __restrict__ mem,
    float* __restrict__ out)
{
    __shared__ float red[256];
    __shared__ int   redi[256];
    __shared__ float inv_x_s;
    const int b = blockIdx.x, tid = threadIdx.x;
    float lx = latent[(size_t)b * 256 + tid];
    red[tid] = lx * lx;
    __syncthreads();
    for (int s = 128; s > 0; s >>= 1) {
        if (tid < s) red[tid] += red[tid + s];
        __syncthreads();
    }
    if (tid == 0) inv_x_s = 1.f / fmaxf(sqrtf(red[0]), 1e-12f);
    __syncthreads();
    const float inv_x = inv_x_s;

    float vals[16];
    for (int j = 0; j < 16; ++j) {
        int m = tid + j * 256;
        vals[j] = dots[(size_t)b * 4096 + m] * inv_mn[m] * inv_x;
    }
    float tv[10]; int ti[10];
    for (int t = 0; t < 10; ++t) {
        float bv = -1e30f; int bidx = 0x7fffffff;
        for (int j = 0; j < 16; ++j) {
            int m = tid + j * 256;
            float v = vals[j];
            if (v > bv || (v == bv && m < bidx)) { bv = v; bidx = m; }
        }
        red[tid] = bv; redi[tid] = bidx;
        __syncthreads();
        for (int s = 128; s > 0; s >>= 1) {
            if (tid < s) {
                float v2 = red[tid + s]; int i2 = redi[tid + s];
                if (v2 > red[tid] || (v2 == red[tid] && i2 < redi[tid])) { red[tid] = v2; redi[tid] = i2; }
            }
            __syncthreads();
        }
        int sel = redi[0];
        tv[t] = red[0]; ti[t] = sel;
        if ((sel & 255) == tid) vals[sel >> 8] = -1e30f;
        __syncthreads();
    }
    float w[10], wsum = 0.f;
    for (int t = 0; t < 10; ++t) { w[t] = expf(tv[t] - tv[0]); wsum += w[t]; }
    float inv_ws = 1.f / wsum;
    float acc = 0.f;
    for (int t = 0; t < 10; ++t) acc += (w[t] * inv_ws) * mem[(size_t)ti[t] * 256 + tid];
    out[(size_t)b * 256 + tid] = acc;
}

// ---------------------------------------------------------------------------
// Weight repack.
//   pk1[c64][q4][tap4][o32]  from upt1_w [64][32][4][4]   (ConvT subpixel)
//   pk2[c32][tap9][o32]      from c1_w   [32][32][3][3]
//   pk3[c32][q4][tap4][o16]  from upt2_w [32][16][4][4]
//   pk4[c16][tap9][o8]       from c2_w   [8][16][3][3]
//   pk5[blk2][j128][c32]     from blk_ff2_w [2][32][128]  (transpose)
// ---------------------------------------------------------------------------
__global__ __launch_bounds__(256) void k_pack(
    const float* __restrict__ wt1, const float* __restrict__ wc1,
    const float* __restrict__ wt2, const float* __restrict__ wc2,
    const float* __restrict__ w2src,
    float* __restrict__ pk1, float* __restrict__ pk2,
    float* __restrict__ pk3, float* __restrict__ pk4,
    float* __restrict__ pk5)
{
    int i = blockIdx.x * 256 + threadIdx.x;
    if (i < 32768) {
        int o = i & 31, t = (i >> 5) & 3, q = (i >> 7) & 3, c = i >> 9;
        int wy = t >> 1, wx = t & 1, py = q >> 1, px = q & 1;
        int ky = 3 - py - 2 * wy, kx = 3 - px - 2 * wx;
        pk1[i] = wt1[((c * 32 + o) * 4 + ky) * 4 + kx];
    }
    if (i < 9216) {
        int o = i & 31, tap = (i >> 5) % 9, c = i / 288;
        pk2[i] = wc1[(o * 32 + c) * 9 + tap];
    }
    if (i < 8192) {
        int o = i & 15, t = (i >> 4) & 3, q = (i >> 6) & 3, c = i >> 8;
        int wy = t >> 1, wx = t & 1, py = q >> 1, px = q & 1;
        int ky = 3 - py - 2 * wy, kx = 3 - px - 2 * wx;
        pk3[i] = wt2[((c * 16 + o) * 4 + ky) * 4 + kx];
    }
    if (i < 1152) {
        int o = i & 7, tap = (i >> 3) % 9, c = i / 72;
        pk4[i] = wc2[(o * 16 + c) * 9 + tap];
    }
    if (i < 8192) {
        int c = i & 31, j = (i >> 5) & 127, bq = i >> 12;
        pk5[i] = w2src[bq * 4096 + c * 128 + j];
    }
}

// ---------------------------------------------------------------------------
// ConvTranspose2d 64->32 k4 s2 p1, 7x7 -> 14x14, ReLU. 1 sample/block.
// ---------------------------------------------------------------------------
__global__ __launch_bounds__(256) void k_convt1(
    const float* __restrict__ in, const float* __restrict__ pk1,
    const float* __restrict__ bias, float* __restrict__ out)
{
    __shared__ float P[64 * 108];   // [c][9 rows][12 cols], zero-padded
    const int b = blockIdx.x, tid = threadIdx.x;
    for (int e = tid; e < 6912; e += 256) P[e] = 0.f;
    __syncthreads();
    for (int e = tid; e < 3136; e += 256) {
        int c = e / 49, p = e % 49;
        P[c * 108 + (p / 7 + 1) * 12 + (p % 7 + 1)] = in[(size_t)b * 3136 + e];
    }
    __syncthreads();

    const int q  = __builtin_amdgcn_readfirstlane(tid >> 6);
    const int py = q >> 1, px = q & 1;
    const int lane = tid & 63;
    const bool active = lane < 56;
    int ty = lane >> 3, tx = lane & 7;
    if (!active) { ty = 0; tx = 0; }
    const bool do_store = active && (tx < 7);
    const int rbase = ty + py, cbase = tx + px;

    float acc[32];
    #pragma unroll
    for (int o = 0; o < 32; ++o) acc[o] = 0.f;

    for (int c = 0; c < 64; ++c) {
        const float* Pc = &P[c * 108 + rbase * 12 + cbase];
        float vin[4];
        vin[0] = Pc[0]; vin[1] = Pc[1]; vin[2] = Pc[12]; vin[3] = Pc[13];
        const float* wq = pk1 + (size_t)((c * 4 + q) * 4) * 32;
        #pragma unroll
        for (int t = 0; t < 4; ++t) {
            const float* wt = wq + t * 32;
            float v = vin[t];
            #pragma unroll
            for (int o = 0; o < 32; ++o) acc[o] = fmaf(v, wt[o], acc[o]);
        }
    }
    if (do_store) {
        const int y = 2 * ty + py, xx = 2 * tx + px;
        float* op = out + (size_t)b * 6272 + y * 14 + xx;
        #pragma unroll
        for (int o = 0; o < 32; ++o) op[o * 196] = fmaxf(acc[o] + bias[o], 0.f);
    }
}

// ---------------------------------------------------------------------------
// Conv2d 32->32 k3 p1, 14x14, ReLU. 2 samples/block.
// ---------------------------------------------------------------------------
__global__ __launch_bounds__(256) void k_conv1(
    const float* __restrict__ in, const float* __restrict__ pk2,
    const float* __restrict__ bias, float* __restrict__ out)
{
    __shared__ float P[8208];   // [s2][c16][16 rows][16 cols] + overread pad
    const int tid = threadIdx.x;
    const int wv = __builtin_amdgcn_readfirstlane(tid >> 6);
    const int og = wv & 1, s = wv >> 1;
    const int lane = tid & 63;
    const bool active = lane < 56;
    int row = lane >> 2, tx0 = (lane & 3) * 4;
    if (!active) { row = 0; tx0 = 0; }
    const size_t b = (size_t)blockIdx.x * 2 + s;

    float acc[4][16];
    #pragma unroll
    for (int i = 0; i < 4; ++i)
        #pragma unroll
        for (int o = 0; o < 16; ++o) acc[i][o] = 0.f;

    for (int cc = 0; cc < 32; cc += 16) {
        __syncthreads();
        for (int e = tid; e < 8208; e += 256) P[e] = 0.f;
        __syncthreads();
        for (int e = tid; e < 6272; e += 256) {
            int si = e / 3136, rem = e - si * 3136;
            int c = rem / 196, p = rem % 196;
            P[((si * 16 + c) * 16 + p / 14 + 1) * 16 + (p % 14 + 1)] =
                in[((size_t)(blockIdx.x * 2 + si) * 32 + cc + c) * 196 + p];
        }
        __syncthreads();
        for (int cl = 0; cl < 16; ++cl) {
            const float* Pb = &P[((s * 16 + cl) * 16 + row) * 16 + tx0];
            float rowb[3][8];
            #pragma unroll
            for (int ky = 0; ky < 3; ++ky) {
                float4 a = *(const float4*)&Pb[ky * 16];
                float4 bq = *(const float4*)&Pb[ky * 16 + 4];
                rowb[ky][0] = a.x; rowb[ky][1] = a.y; rowb[ky][2] = a.z; rowb[ky][3] = a.w;
                rowb[ky][4] = bq.x; rowb[ky][5] = bq.y; rowb[ky][6] = bq.z; rowb[ky][7] = bq.w;
            }
            const float* wbase = pk2 + (size_t)(cc + cl) * 288 + og * 16;
            #pragma unroll
            for (int ky = 0; ky < 3; ++ky) {
                #pragma unroll
                for (int kx = 0; kx < 3; ++kx) {
                    const float* wt = wbase + (ky * 3 + kx) * 32;
                    #pragma unroll
                    for (int o = 0; o < 16; ++o) {
                        float w = wt[o];
                        #pragma unroll
                        for (int i = 0; i < 4; ++i)
                            acc[i][o] = fmaf(rowb[ky][i + kx], w, acc[i][o]);
                    }
                }
            }
        }
    }
    if (active) {
        #pragma unroll
        for (int o = 0; o < 16; ++o) {
            int oo = og * 16 + o;
            float bo = bias[oo];
            #pragma unroll
            for (int i = 0; i < 4; ++i) {
                int xx = tx0 + i;
                if (xx < 14)
                    out[(b * 32 + oo) * 196 + row * 14 + xx] = fmaxf(acc[i][o] + bo, 0.f);
            }
        }
    }
}

// ---------------------------------------------------------------------------
// ConvTranspose2d 32->16 k4 s2 p1, 14x14 -> 28x28, ReLU. 1 sample/block.
// ---------------------------------------------------------------------------
__global__ __launch_bounds__(256) void k_convt2(
    const float* __restrict__ in, const float* __restrict__ pk3,
    const float* __restrict__ bias, float* __restrict__ out)
{
    __shared__ float P[32 * 320];   // [c][16 rows][20 cols], zero-padded
    const int b = blockIdx.x, tid = threadIdx.x;
    for (int e = tid; e < 10240; e += 256) P[e] = 0.f;
    __syncthreads();
    for (int e = tid; e < 6272; e += 256) {
        int c = e / 196, p = e % 196;
        P[c * 320 + (p / 14 + 1) * 20 + (p % 14 + 1)] = in[(size_t)b * 6272 + e];
    }
    __syncthreads();

    const int q  = __builtin_amdgcn_readfirstlane(tid >> 6);
    const int py = q >> 1, px = q & 1;
    const int lane = tid & 63;
    const bool active = lane < 56;
    int ty = lane >> 2, tx0 = (lane & 3) * 4;
    if (!active) { ty = 0; tx0 = 0; }
    const int rbase = ty + py;

    float acc[4][16];
    #pragma unroll
    for (int i = 0; i < 4; ++i)
        #pragma unroll
        for (int o = 0; o < 16; ++o) acc[i][o] = 0.f;

    for (int c = 0; c < 32; ++c) {
        const float* Pb = &P[c * 320 + rbase * 20 + tx0];
        float raw[2][8];
        #pragma unroll
        for (int r2 = 0; r2 < 2; ++r2) {
            float4 a = *(const float4*)&Pb[r2 * 20];
            float4 bq = *(const float4*)&Pb[r2 * 20 + 4];
            raw[r2][0] = a.x; raw[r2][1] = a.y; raw[r2][2] = a.z; raw[r2][3] = a.w;
            raw[r2][4] = bq.x; raw[r2][5] = bq.y; raw[r2][6] = bq.z; raw[r2][7] = bq.w;
        }
        float rs[2][5];
        #pragma unroll
        for (int r2 = 0; r2 < 2; ++r2)
            #pragma unroll
            for (int j = 0; j < 5; ++j) rs[r2][j] = px ? raw[r2][j + 1] : raw[r2][j];
        const float* wq = pk3 + (size_t)((c * 4 + q) * 4) * 16;
        #pragma unroll
        for (int t = 0; t < 4; ++t) {
            int wy = t >> 1, wx = t & 1;
            const float* wt = wq + t * 16;
            #pragma unroll
            for (int o = 0; o < 16; ++o) {
                float w = wt[o];
                #pragma unroll
                for (int i = 0; i < 4; ++i)
                    acc[i][o] = fmaf(rs[wy][i + wx], w, acc[i][o]);
            }
        }
    }
    if (active) {
        const int y = 2 * ty + py;
        #pragma unroll
        for (int i = 0; i < 4; ++i) {
            int xt = tx0 + i;
            if (xt < 14) {
                int xx = 2 * xt + px;
                #pragma unroll
                for (int o = 0; o < 16; ++o)
                    out[((size_t)b * 16 + o) * 784 + y * 28 + xx] = fmaxf(acc[i][o] + bias[o], 0.f);
            }
        }
    }
}

// ---------------------------------------------------------------------------
// Conv2d 16->8 k3 p1 + ReLU fused with Conv2d 8->1 k1. 1 sample/block.
// ---------------------------------------------------------------------------
__global__ __launch_bounds__(256) void k_conv23(
    const float* __restrict__ in, const float* __restrict__ pk4,
    const float* __restrict__ b2, const float* __restrict__ w3,
    const float* __restrict__ b3, float* __restrict__ out)
{
    __shared__ float P[8 * 960];   // [c8][30 rows][32 cols], zero-padded
    const int b = blockIdx.x, tid = threadIdx.x;
    const bool active = tid < 196;
    int row = tid / 7, tx0 = (tid % 7) * 4;
    if (!active) { row = 0; tx0 = 0; }

    float acc[4][8];
    #pragma unroll
    for (int i = 0; i < 4; ++i)
        #pragma unroll
        for (int o = 0; o < 8; ++o) acc[i][o] = 0.f;

    for (int cc = 0; cc < 16; cc += 8) {
        __syncthreads();
        for (int e = tid; e < 7680; e += 256) P[e] = 0.f;
        __syncthreads();
        for (int e = tid; e < 6272; e += 256) {
            int c = e / 784, p = e % 784;
            P[(c * 30 + p / 28 + 1) * 32 + (p % 28 + 1)] =
                in[(size_t)b * 12544 + (cc + c) * 784 + p];
        }
        __syncthreads();
        for (int cl = 0; cl < 8; ++cl) {
            const float* Pb = &P[(cl * 30 + row) * 32 + tx0];
            const float* wb = pk4 + (size_t)(cc + cl) * 72;
            #pragma unroll
            for (int ky = 0; ky < 3; ++ky) {
                float4 a = *(const float4*)&Pb[ky * 32];
                float4 bq = *(const float4*)&Pb[ky * 32 + 4];
                float rowb[8] = {a.x, a.y, a.z, a.w, bq.x, bq.y, bq.z, bq.w};
                #pragma unroll
                for (int kx = 0; kx < 3; ++kx) {
                    const float* wt = wb + (ky * 3 + kx) * 8;
                    #pragma unroll
                    for (int o = 0; o < 8; ++o) {
                        float w = wt[o];
                        #pragma unroll
                        for (int i = 0; i < 4; ++i)
                            acc[i][o] = fmaf(rowb[i + kx], w, acc[i][o]);
                    }
                }
            }
        }
    }
    if (active) {
        const float bias3 = b3[0];
        #pragma unroll
        for (int i = 0; i < 4; ++i) {
            float r = bias3;
            #pragma unroll
            for (int o = 0; o < 8; ++o) r += fmaxf(acc[i][o] + b2[o], 0.f) * w3[o];
            out[(size_t)b * 784 + row * 28 + tx0 + i] = r;
        }
    }
}

// ---------------------------------------------------------------------------
extern "C" void kernel_launch(void* const* d_in, const int* in_sizes, int n_in,
                              void* d_out, int out_size, void* d_ws, size_t ws_size,
                              hipStream_t stream)
{
    const float* x       = (const float*)d_in[0];
    const float* patch_w = (const float*)d_in[1];
    const float* patch_b = (const float*)d_in[2];
    const float* ln1g    = (const float*)d_in[3];
    const float* ln1b    = (const float*)d_in[4];
    const float* wi      = (const float*)d_in[5];
    const float* bi      = (const float*)d_in[6];
    const float* wo      = (const float*)d_in[7];
    const float* bo      = (const float*)d_in[8];
    const float* ln2g    = (const float*)d_in[9];
    const float* ln2b    = (const float*)d_in[10];
    const float* w1      = (const float*)d_in[11];
    const float* b1      = (const float*)d_in[12];
    const float* w2      = (const float*)d_in[13];
    const float* b2      = (const float*)d_in[14];
    const float* lat_w   = (const float*)d_in[15];
    const float* lat_b   = (const float*)d_in[16];
    const float* memory  = (const float*)d_in[17];
    const float* dec_w   = (const float*)d_in[18];
    const float* dec_b   = (const float*)d_in[19];
    const float* upt1_w  = (const float*)d_in[20];
    const float* upt1_b  = (const float*)d_in[21];
    const float* c1_w    = (const float*)d_in[22];
    const float* c1_b    = (const float*)d_in[23];
    const float* upt2_w  = (const float*)d_in[24];
    const float* upt2_b  = (const float*)d_in[25];
    const float* c2_w    = (const float*)d_in[26];
    const float* c2_b    = (const float*)d_in[27];
    const float* c3_w    = (const float*)d_in[28];
    const float* c3_b    = (const float*)d_in[29];
    float* outp = (float*)d_out;

    float* ws = (float*)d_ws;
    size_t off = 0;
    auto alloc = [&](size_t n) { float* p = ws + off; off += (n + 63) & ~(size_t)63; return p; };
    float* tokens     = alloc((size_t)B_TOT * 1568);
    float* latent     = alloc((size_t)B_TOT * 256);
    float* dots       = alloc((size_t)B_TOT * 4096);
    float* mem_latent = alloc((size_t)B_TOT * 256);
    float* inv_mn     = alloc(4096);
    float* pk1        = alloc(32768);
    float* pk2        = alloc(9216);
    float* pk3        = alloc(8192);
    float* pk4        = alloc(1152);
    float* pk5        = alloc(8192);
    float* d0         = alloc((size_t)CHUNK * 3136);
    float* d1         = alloc((size_t)CHUNK * 6272);
    float* d2         = alloc((size_t)CHUNK * 6272);
    float* d3         = alloc((size_t)CHUNK * 12544);
    (void)in_sizes; (void)n_in; (void)out_size; (void)ws_size;

    // Weight repack (decoder convs + encoder FF2 transpose)
    k_pack<<<128, 256, 0, stream>>>(upt1_w, c1_w, upt2_w, c2_w, w2,
                                    pk1, pk2, pk3, pk4, pk5);

    // Encoder (wave-per-sample)
    k_tokens<<<B_TOT / 4, 256, 0, stream>>>(x, patch_w, patch_b, ln1g, ln1b, wi, bi,
                                            wo, bo, ln2g, ln2b, w1, b1, pk5, b2, tokens);
    k_gemm<<<dim3(256 / 64, B_TOT / 64), 256, 0, stream>>>(tokens, lat_w, lat_b, latent,
                                                           B_TOT, 256, 1568);
    k_mnorm<<<4096, 256, 0, stream>>>(memory, inv_mn);
    k_gemm<<<dim3(4096 / 64, B_TOT / 64), 256, 0, stream>>>(latent, memory, nullptr, dots,
                                                            B_TOT, 4096, 256);
    k_memread<<<B_TOT, 256, 0, stream>>>(latent, dots, inv_mn, memory, mem_latent);

    // Decoder, chunked over batch
    for (int c = 0; c < B_TOT / CHUNK; ++c) {
        const float* ml = mem_latent + (size_t)c * CHUNK * 256;
        k_gemm<<<dim3(3136 / 64, CHUNK / 64), 256, 0, stream>>>(ml, dec_w, dec_b, d0,
                                                                CHUNK, 3136, 256);
        k_convt1<<<CHUNK, 256, 0, stream>>>(d0, pk1, upt1_b, d1);
        k_conv1 <<<CHUNK / 2, 256, 0, stream>>>(d1, pk2, c1_b, d2);
        k_convt2<<<CHUNK, 256, 0, stream>>>(d2, pk3, upt2_b, d3);
        k_conv23<<<CHUNK, 256, 0, stream>>>(d3, pk4, c2_b, c3_w, c3_b,
                                            outp + (size_t)c * CHUNK * 784);
    }
}